// Round 1
// baseline (4434.600 us; speedup 1.0000x reference)
//
#include <hip/hip_runtime.h>
#include <hip/hip_bf16.h>
#include <math.h>

#define KNN 20
constexpr int NPTS = 2048;   // N
constexpr int NBAT = 8;      // B
constexpr int M_TOT = NBAT * NPTS;  // 16384

// ---------------------------------------------------------------- sq norms
__global__ __launch_bounds__(256) void sqnorm_kernel(const float* __restrict__ X, int lda, int C,
                                                     float* __restrict__ sq) {
  int i = blockIdx.x * 256 + threadIdx.x;
  if (i >= M_TOT) return;
  const float* p = X + (size_t)i * lda;
  float s = 0.f;
  for (int c = 0; c < C; ++c) { float v = p[c]; s = fmaf(v, v, s); }
  sq[i] = s;
}

// ---------------------------------------------------------------- kNN (dist + top-20 fused)
// grid: (N/64, B), block 256.  4 threads per query row; each thread scans 512 j's,
// keeps a sorted top-20 (static-index swap chain), then 4-way lexicographic merge.
#define INSERT_CAND(key_, j_)                                  \
  if ((key_) < dl[KNN - 1]) {                                  \
    float _k = (key_); int _j = (j_);                          \
    _Pragma("unroll")                                          \
    for (int p = 0; p < KNN; ++p) {                            \
      bool sw = _k < dl[p];                                    \
      float od = dl[p]; int oi = il[p];                        \
      dl[p] = sw ? _k : od; il[p] = sw ? _j : oi;              \
      _k = sw ? od : _k; _j = sw ? oi : _j;                    \
    }                                                          \
  }

template <int C>
__global__ __launch_bounds__(256) void knn_kernel(const float* __restrict__ X, int lda,
                                                  const float* __restrict__ sq,
                                                  int* __restrict__ knn_out) {
  constexpr int CP = (C == 3) ? 4 : (C + 4);  // pad: float4-aligned, bank-spread
  __shared__ float xi[64][CP];
  __shared__ float md[64][4][KNN];
  __shared__ int   mi[64][4][KNN];

  const int b = blockIdx.y;
  const int m0 = blockIdx.x * 64;
  const int t = threadIdx.x;
  const int r = t >> 2, sub = t & 3;

  for (int e = t; e < 64 * C; e += 256) {
    int rr = e / C, cc = e % C;
    xi[rr][cc] = X[(size_t)(b * NPTS + m0 + rr) * lda + cc];
  }
  __syncthreads();

  float dl[KNN]; int il[KNN];
#pragma unroll
  for (int p = 0; p < KNN; ++p) { dl[p] = INFINITY; il[p] = 0x7fffffff; }

  const float* Xb = X + (size_t)b * NPTS * lda;
  const float* sqb = sq + b * NPTS;

  for (int jj = 0; jj < NPTS; jj += 8) {
    const int j1 = jj + sub, j2 = jj + 4 + sub;
    const float* p1 = Xb + (size_t)j1 * lda;
    const float* p2 = Xb + (size_t)j2 * lda;
    float a1 = 0.f, a2 = 0.f;
    if constexpr (C == 3) {
      float x0 = xi[r][0], x1 = xi[r][1], x2 = xi[r][2];
      a1 = fmaf(x0, p1[0], fmaf(x1, p1[1], x2 * p1[2]));
      a2 = fmaf(x0, p2[0], fmaf(x1, p2[1], x2 * p2[2]));
    } else {
#pragma unroll
      for (int c = 0; c < C; c += 4) {
        float4 xv = *(const float4*)(&xi[r][c]);
        float4 v1 = *(const float4*)(p1 + c);
        float4 v2 = *(const float4*)(p2 + c);
        a1 = fmaf(xv.x, v1.x, a1); a1 = fmaf(xv.y, v1.y, a1);
        a1 = fmaf(xv.z, v1.z, a1); a1 = fmaf(xv.w, v1.w, a1);
        a2 = fmaf(xv.x, v2.x, a2); a2 = fmaf(xv.y, v2.y, a2);
        a2 = fmaf(xv.z, v2.z, a2); a2 = fmaf(xv.w, v2.w, a2);
      }
    }
    // ranking key: sq_j - 2*dot  (== d - sq_i, same ordering as reference)
    float k1 = fmaf(-2.f, a1, sqb[j1]);
    float k2 = fmaf(-2.f, a2, sqb[j2]);
    INSERT_CAND(k1, j1)
    INSERT_CAND(k2, j2)
  }

#pragma unroll
  for (int p = 0; p < KNN; ++p) { md[r][sub][p] = dl[p]; mi[r][sub][p] = il[p]; }
  __syncthreads();

  if (t < 64) {
    int pp[4] = {0, 0, 0, 0};
    int* orow = knn_out + (size_t)(b * NPTS + m0 + t) * KNN;
    for (int k = 0; k < KNN; ++k) {
      float bd = md[t][0][pp[0]]; int bi = mi[t][0][pp[0]]; int bs = 0;
#pragma unroll
      for (int s = 1; s < 4; ++s) {
        float dd = md[t][s][pp[s]]; int ii = mi[t][s][pp[s]];
        if (dd < bd || (dd == bd && ii < bi)) { bd = dd; bi = ii; bs = s; }
      }
      orow[k] = bi;
      pp[bs]++;
    }
  }
}

// ---------------------------------------------------------------- weight prep: [Wd ; Wc-Wd]
__global__ __launch_bounds__(256) void wcat_kernel(const float* __restrict__ W, int O, int Cc,
                                                   float* __restrict__ out) {
  int i = blockIdx.x * 256 + threadIdx.x;
  if (i >= O * Cc) return;
  int o = i / Cc, c = i % Cc;
  float wd = W[(size_t)o * 2 * Cc + c];
  float wc = W[(size_t)o * 2 * Cc + Cc + c];
  out[(size_t)o * Cc + c] = wd;              // rows 0..O-1   : v = Wd * x
  out[(size_t)(O + o) * Cc + c] = wc - wd;   // rows O..2O-1  : u = (Wc-Wd) * x
}

// ---------------------------------------------------------------- fp32 tiled GEMM
// out[M, NO] = A[M, K](lda) @ Wt[NO, K]^T ;  BM=BN=64, BK=16, 256 thr, 4x4 micro-tile
template <bool FUSE>
__global__ __launch_bounds__(256) void gemm_kernel(const float* __restrict__ A, int lda, int K,
                                                   const float* __restrict__ Wt, int NO,
                                                   float* __restrict__ out,
                                                   const float* __restrict__ bn) {
  __shared__ float As[16][68];
  __shared__ float Bs[16][68];
  const int t = threadIdx.x;
  const int tx = t & 15, ty = t >> 4;
  const int m0 = blockIdx.x * 64, n0 = blockIdx.y * 64;
  float acc[4][4] = {};

  for (int k0 = 0; k0 < K; k0 += 16) {
#pragma unroll
    for (int q = 0; q < 4; ++q) {
      int e = t + q * 256;
      int rr = e >> 4, cc = e & 15;
      int kk = k0 + cc;
      As[cc][rr] = (kk < K) ? A[(size_t)(m0 + rr) * lda + kk] : 0.f;
      Bs[cc][rr] = (kk < K) ? Wt[(size_t)(n0 + rr) * K + kk] : 0.f;
    }
    __syncthreads();
#pragma unroll
    for (int kk = 0; kk < 16; ++kk) {
      float4 av = *(const float4*)(&As[kk][ty * 4]);
      float4 bv = *(const float4*)(&Bs[kk][tx * 4]);
      float a[4] = {av.x, av.y, av.z, av.w};
      float bb[4] = {bv.x, bv.y, bv.z, bv.w};
#pragma unroll
      for (int i = 0; i < 4; ++i)
#pragma unroll
        for (int j = 0; j < 4; ++j) acc[i][j] = fmaf(a[i], bb[j], acc[i][j]);
    }
    __syncthreads();
  }

#pragma unroll
  for (int i = 0; i < 4; ++i) {
    int row = m0 + ty * 4 + i;
#pragma unroll
    for (int j = 0; j < 4; ++j) {
      int col = n0 + tx * 4 + j;
      float v = acc[i][j];
      if constexpr (FUSE) {
        float g = bn[col], be = bn[NO + col], mm = bn[2 * NO + col], va = bn[3 * NO + col];
        float s = g * rsqrtf(va + 1e-5f);
        v = fmaf(s, v - mm, be);
        v = v > 0.f ? v : 0.2f * v;
      }
      out[(size_t)row * NO + col] = v;
    }
  }
}

// ---------------------------------------------------------------- gather + k-max + BN + lrelu
// grid: B*N blocks, block = O threads. out = lrelu(s*(u + max_k v[idx_k] - mean) + beta)
__global__ void gathermax_kernel(const float* __restrict__ uv, const int* __restrict__ knn_in,
                                 const float* __restrict__ bn, int O,
                                 float* __restrict__ outc, int ldo) {
  const int n = blockIdx.x;   // global row b*N + n
  const int o = threadIdx.x;
  __shared__ int js[KNN];
  if (o < KNN) js[o] = knn_in[(size_t)n * KNN + o];
  __syncthreads();
  const int b = n >> 11;
  const int ld2 = 2 * O;
  const float* uvb = uv + (size_t)b * NPTS * ld2;
  float m = -INFINITY;
#pragma unroll
  for (int k = 0; k < KNN; ++k) m = fmaxf(m, uvb[(size_t)js[k] * ld2 + o]);
  float u = uv[(size_t)n * ld2 + O + o];
  float g = bn[o], be = bn[O + o], mm = bn[2 * O + o], va = bn[3 * O + o];
  float s = g * rsqrtf(va + 1e-5f);
  float y = fmaf(s, m + u - mm, be);
  y = y > 0.f ? y : 0.2f * y;
  outc[(size_t)n * ldo + o] = y;
}

// ---------------------------------------------------------------- final global max+avg reduce
__global__ __launch_bounds__(256) void reduce1_kernel(const float* __restrict__ feat,
                                                      float* __restrict__ part) {
  const int sp = blockIdx.x;                 // 16 splits of 128 rows
  const int b = blockIdx.z;
  const int o = blockIdx.y * 256 + threadIdx.x;
  const float* f = feat + ((size_t)b * NPTS + sp * 128) * 1024 + o;
  float mx = -INFINITY, sm = 0.f;
  for (int n = 0; n < 128; ++n) { float v = f[(size_t)n * 1024]; mx = fmaxf(mx, v); sm += v; }
  part[((size_t)(b * 16 + sp)) * 1024 + o] = mx;
  part[131072 + ((size_t)(b * 16 + sp)) * 1024 + o] = sm;
}

__global__ __launch_bounds__(256) void reduce2_kernel(const float* __restrict__ part,
                                                      float* __restrict__ out) {
  const int b = blockIdx.y;
  const int o = blockIdx.x * 256 + threadIdx.x;
  float mx = -INFINITY, sm = 0.f;
  for (int sp = 0; sp < 16; ++sp) {
    mx = fmaxf(mx, part[((size_t)(b * 16 + sp)) * 1024 + o]);
    sm += part[131072 + ((size_t)(b * 16 + sp)) * 1024 + o];
  }
  out[(size_t)b * 2048 + o] = mx;
  out[(size_t)b * 2048 + 1024 + o] = sm * (1.f / 2048.f);
}

// ---------------------------------------------------------------- launch
extern "C" void kernel_launch(void* const* d_in, const int* in_sizes, int n_in,
                              void* d_out, int out_size, void* d_ws, size_t ws_size,
                              hipStream_t stream) {
  const float* x   = (const float*)d_in[0];
  const float* W1  = (const float*)d_in[1];
  const float* W2  = (const float*)d_in[2];
  const float* W3  = (const float*)d_in[3];
  const float* W4  = (const float*)d_in[4];
  const float* W5  = (const float*)d_in[5];
  const float* bn1 = (const float*)d_in[6];
  const float* bn2 = (const float*)d_in[7];
  const float* bn3 = (const float*)d_in[8];
  const float* bn4 = (const float*)d_in[9];
  const float* bn5 = (const float*)d_in[10];
  float* out = (float*)d_out;

  char* ws = (char*)d_ws;
  float* xcat  = (float*)(ws);                 // 16384*512 f32 = 32 MiB
  float* uv    = (float*)(ws + 33554432);      // 16384*1024 f32 = 64 MiB (uv / feat)
  int*   knnb  = (int*)  (ws + 100663296);     // 16384*20 int  = 1.25 MiB
  float* sqb   = (float*)(ws + 101974016);     // 16384 f32
  float* wcat  = (float*)(ws + 102039552);     // <= 512*256 f32
  float* part  = (float*)(ws + 102563840);     // 2*8*16*1024 f32 = 1 MiB

  // ---- Layer 1: x(B,N,3) -> x1(64) @ xcat col 0
  sqnorm_kernel<<<64, 256, 0, stream>>>(x, 3, 3, sqb);
  knn_kernel<3><<<dim3(32, 8), 256, 0, stream>>>(x, 3, sqb, knnb);
  wcat_kernel<<<1, 256, 0, stream>>>(W1, 64, 3, wcat);
  gemm_kernel<false><<<dim3(256, 2), 256, 0, stream>>>(x, 3, 3, wcat, 128, uv, nullptr);
  gathermax_kernel<<<16384, 64, 0, stream>>>(uv, knnb, bn1, 64, xcat + 0, 512);

  // ---- Layer 2: x1(64) -> x2(64) @ xcat col 64
  sqnorm_kernel<<<64, 256, 0, stream>>>(xcat, 512, 64, sqb);
  knn_kernel<64><<<dim3(32, 8), 256, 0, stream>>>(xcat, 512, sqb, knnb);
  wcat_kernel<<<16, 256, 0, stream>>>(W2, 64, 64, wcat);
  gemm_kernel<false><<<dim3(256, 2), 256, 0, stream>>>(xcat, 512, 64, wcat, 128, uv, nullptr);
  gathermax_kernel<<<16384, 64, 0, stream>>>(uv, knnb, bn2, 64, xcat + 64, 512);

  // ---- Layer 3: x2(64) -> x3(128) @ xcat col 128
  sqnorm_kernel<<<64, 256, 0, stream>>>(xcat + 64, 512, 64, sqb);
  knn_kernel<64><<<dim3(32, 8), 256, 0, stream>>>(xcat + 64, 512, sqb, knnb);
  wcat_kernel<<<32, 256, 0, stream>>>(W3, 128, 64, wcat);
  gemm_kernel<false><<<dim3(256, 4), 256, 0, stream>>>(xcat + 64, 512, 64, wcat, 256, uv, nullptr);
  gathermax_kernel<<<16384, 128, 0, stream>>>(uv, knnb, bn3, 128, xcat + 128, 512);

  // ---- Layer 4: x3(128) -> x4(256) @ xcat col 256
  sqnorm_kernel<<<64, 256, 0, stream>>>(xcat + 128, 512, 128, sqb);
  knn_kernel<128><<<dim3(32, 8), 256, 0, stream>>>(xcat + 128, 512, sqb, knnb);
  wcat_kernel<<<128, 256, 0, stream>>>(W4, 256, 128, wcat);
  gemm_kernel<false><<<dim3(256, 8), 256, 0, stream>>>(xcat + 128, 512, 128, wcat, 512, uv, nullptr);
  gathermax_kernel<<<16384, 256, 0, stream>>>(uv, knnb, bn4, 256, xcat + 256, 512);

  // ---- Final MLP: feat = lrelu(bn5(xcat @ W5^T))  (W5 is already (1024,512) row-major)
  gemm_kernel<true><<<dim3(256, 16), 256, 0, stream>>>(xcat, 512, 512, W5, 1024, uv, bn5);

  // ---- global max + mean over N
  reduce1_kernel<<<dim3(16, 4, 8), 256, 0, stream>>>(uv, part);
  reduce2_kernel<<<dim3(4, 8), 256, 0, stream>>>(part, out);

  (void)in_sizes; (void)n_in; (void)out_size; (void)ws_size;
}

// Round 2
// 2077.173 us; speedup vs baseline: 2.1349x; 2.1349x over previous
//
#include <hip/hip_runtime.h>
#include <hip/hip_bf16.h>
#include <math.h>

#define KNN 20
constexpr int NPTS = 2048;   // N
constexpr int NBAT = 8;      // B
constexpr int M_TOT = NBAT * NPTS;  // 16384

// ---------------------------------------------------------------- sq norms
__global__ __launch_bounds__(256) void sqnorm_kernel(const float* __restrict__ X, int lda, int C,
                                                     float* __restrict__ sq) {
  int i = blockIdx.x * 256 + threadIdx.x;
  if (i >= M_TOT) return;
  const float* p = X + (size_t)i * lda;
  float s = 0.f;
  for (int c = 0; c < C; ++c) { float v = p[c]; s = fmaf(v, v, s); }
  sq[i] = s;
}

// ---------------------------------------------------------------- top-20 sorted insert (swap chain)
#define INSERT_CAND(key_, j_)                                  \
  if ((key_) < dl[KNN - 1]) {                                  \
    float _k = (key_); int _j = (j_);                          \
    _Pragma("unroll")                                          \
    for (int p = 0; p < KNN; ++p) {                            \
      bool sw = _k < dl[p];                                    \
      float od = dl[p]; int oi = il[p];                        \
      dl[p] = sw ? _k : od; il[p] = sw ? _j : oi;              \
      _k = sw ? od : _k; _j = sw ? oi : _j;                    \
    }                                                          \
  }

// ---------------------------------------------------------------- kNN: GEMM-shaped dist + fused select
// Block: 256 thr. Tile: 64 rows x 64 cands/chunk, micro-tile 4x4 (rows ty+16i, cands tx+16j).
// K-blocked LDS staging (KB=32). Candidates split CSPLIT ways across blockIdx.y.
// Each thread keeps a register top-20 of its 128-candidate stream (4 select-threads/row),
// writes partial (d,idx) lists to global; knnmerge_kernel does the exact 16-way lex merge.
template <int C, int CSPLIT>
__global__ __launch_bounds__(256) void knn2_kernel(const float* __restrict__ X, int lda,
                                                   const float* __restrict__ sq,
                                                   float* __restrict__ pd, int* __restrict__ pi) {
  constexpr int ROWS = 64, CHK = 64, KB = 32, SEL = 4;
  constexpr int KP = KB + 4;                  // 36 floats: pad -> conflict-free f4 reads
  constexpr int DP = 65;                      // dist stride: 2-way max on select reads
  constexpr int NKB = (C == 3) ? 1 : C / KB;
  constexpr int XI_W = (C == 3) ? 4 : KP;
  constexpr int SMF = ROWS * XI_W * 2 + ROWS * DP;
  __shared__ __align__(16) float smem[SMF];
  float* xi = smem;                           // [ROWS][XI_W]
  float* xj = smem + ROWS * XI_W;             // [CHK][XI_W]
  float* dist = smem + 2 * ROWS * XI_W;       // [ROWS][DP]

  const int b = blockIdx.z;
  const int m0 = blockIdx.x * ROWS;
  const int jsplit = blockIdx.y * (NPTS / CSPLIT);
  const int t = threadIdx.x;
  const int tx = t & 15, ty = t >> 4;         // compute roles
  const int sr = t >> 2, ss = t & 3;          // select roles
  const float* Xb = X + (size_t)b * NPTS * lda;
  const float* sqb = sq + b * NPTS;

  float dl[KNN]; int il[KNN];
#pragma unroll
  for (int p = 0; p < KNN; ++p) { dl[p] = INFINITY; il[p] = 0x7fffffff; }

  for (int c0 = 0; c0 < NPTS / CSPLIT; c0 += CHK) {
    const int jb = jsplit + c0;
    float acc[4][4] = {};

    if constexpr (C == 3) {
      __syncthreads();
      if (t < ROWS * 3) {
        int rr = t / 3, cc = t % 3;
        xi[rr * 4 + cc] = Xb[(size_t)(m0 + rr) * lda + cc];
        xj[rr * 4 + cc] = Xb[(size_t)(jb + rr) * lda + cc];
      }
      __syncthreads();
#pragma unroll
      for (int i = 0; i < 4; ++i) {
        const float* xr = xi + (ty + 16 * i) * 4;
        float x0 = xr[0], x1 = xr[1], x2 = xr[2];
#pragma unroll
        for (int j = 0; j < 4; ++j) {
          const float* xc = xj + (tx + 16 * j) * 4;
          acc[i][j] = fmaf(x0, xc[0], fmaf(x1, xc[1], x2 * xc[2]));
        }
      }
    } else {
#pragma unroll
      for (int kb = 0; kb < NKB; ++kb) {
        __syncthreads();
        // stage 64x32 f32 of xi and xj (512 float4 each; 2 per thread per buffer)
#pragma unroll
        for (int q = 0; q < 2; ++q) {
          int e = t + q * 256;
          int rr = e >> 3, cc = e & 7;
          *(float4*)(xi + rr * KP + cc * 4) =
              *(const float4*)(Xb + (size_t)(m0 + rr) * lda + kb * KB + cc * 4);
          *(float4*)(xj + rr * KP + cc * 4) =
              *(const float4*)(Xb + (size_t)(jb + rr) * lda + kb * KB + cc * 4);
        }
        __syncthreads();
#pragma unroll
        for (int k4 = 0; k4 < KB / 4; ++k4) {
          float4 av[4], bv[4];
#pragma unroll
          for (int i = 0; i < 4; ++i) av[i] = *(const float4*)(xi + (ty + 16 * i) * KP + k4 * 4);
#pragma unroll
          for (int j = 0; j < 4; ++j) bv[j] = *(const float4*)(xj + (tx + 16 * j) * KP + k4 * 4);
#pragma unroll
          for (int i = 0; i < 4; ++i)
#pragma unroll
            for (int j = 0; j < 4; ++j) {
              acc[i][j] = fmaf(av[i].x, bv[j].x, acc[i][j]);
              acc[i][j] = fmaf(av[i].y, bv[j].y, acc[i][j]);
              acc[i][j] = fmaf(av[i].z, bv[j].z, acc[i][j]);
              acc[i][j] = fmaf(av[i].w, bv[j].w, acc[i][j]);
            }
        }
      }
    }

    // ranking key: sq_j - 2*dot (same ordering as reference d; bit-identical to round 1)
    float sqv[4];
#pragma unroll
    for (int j = 0; j < 4; ++j) sqv[j] = sqb[jb + tx + 16 * j];
#pragma unroll
    for (int i = 0; i < 4; ++i)
#pragma unroll
      for (int j = 0; j < 4; ++j)
        dist[(ty + 16 * i) * DP + tx + 16 * j] = fmaf(-2.f, acc[i][j], sqv[j]);
    __syncthreads();

    // select: 4 threads/row, each scans 16 cands (ascending j within thread)
#pragma unroll
    for (int q = 0; q < 16; ++q) {
      float key = dist[sr * DP + ss * 16 + q];
      int jidx = jb + ss * 16 + q;
      INSERT_CAND(key, jidx)
    }
  }

  // write partial top-20 lists
  const size_t grow = (size_t)(b * NPTS + m0 + sr);
  const int g = blockIdx.y * SEL + ss;
  float* od = pd + (grow * (CSPLIT * SEL) + g) * KNN;
  int* oi = pi + (grow * (CSPLIT * SEL) + g) * KNN;
#pragma unroll
  for (int p = 0; p < KNN; ++p) { od[p] = dl[p]; oi[p] = il[p]; }
}

// ---------------------------------------------------------------- exact NL-way merge of sorted lists
template <int NL>
__global__ __launch_bounds__(256) void knnmerge_kernel(const float* __restrict__ pd,
                                                       const int* __restrict__ pi,
                                                       int* __restrict__ knn_out) {
  int row = blockIdx.x * 256 + threadIdx.x;
  if (row >= M_TOT) return;
  const float* d = pd + (size_t)row * NL * KNN;
  const int* ii = pi + (size_t)row * NL * KNN;
  int p[NL];
#pragma unroll
  for (int g = 0; g < NL; ++g) p[g] = 0;
  int* orow = knn_out + (size_t)row * KNN;
  for (int k = 0; k < KNN; ++k) {
    float bd = INFINITY; int bi = 0x7fffffff; int bg = 0;
#pragma unroll
    for (int g = 0; g < NL; ++g) {
      float dd = d[g * KNN + p[g]];
      int iv = ii[g * KNN + p[g]];
      if (dd < bd || (dd == bd && iv < bi)) { bd = dd; bi = iv; bg = g; }
    }
    orow[k] = bi;
#pragma unroll
    for (int g = 0; g < NL; ++g) p[g] += (bg == g) ? 1 : 0;   // static-index update
  }
}

// ---------------------------------------------------------------- weight prep: [Wd ; Wc-Wd]
__global__ __launch_bounds__(256) void wcat_kernel(const float* __restrict__ W, int O, int Cc,
                                                   float* __restrict__ out) {
  int i = blockIdx.x * 256 + threadIdx.x;
  if (i >= O * Cc) return;
  int o = i / Cc, c = i % Cc;
  float wd = W[(size_t)o * 2 * Cc + c];
  float wc = W[(size_t)o * 2 * Cc + Cc + c];
  out[(size_t)o * Cc + c] = wd;              // rows 0..O-1   : v = Wd * x
  out[(size_t)(O + o) * Cc + c] = wc - wd;   // rows O..2O-1  : u = (Wc-Wd) * x
}

// ---------------------------------------------------------------- fp32 tiled GEMM
// out[M, NO] = A[M, K](lda) @ Wt[NO, K]^T ;  BM=BN=64, BK=16, 256 thr, 4x4 micro-tile
template <bool FUSE>
__global__ __launch_bounds__(256) void gemm_kernel(const float* __restrict__ A, int lda, int K,
                                                   const float* __restrict__ Wt, int NO,
                                                   float* __restrict__ out,
                                                   const float* __restrict__ bn) {
  __shared__ float As[16][68];
  __shared__ float Bs[16][68];
  const int t = threadIdx.x;
  const int tx = t & 15, ty = t >> 4;
  const int m0 = blockIdx.x * 64, n0 = blockIdx.y * 64;
  float acc[4][4] = {};

  for (int k0 = 0; k0 < K; k0 += 16) {
#pragma unroll
    for (int q = 0; q < 4; ++q) {
      int e = t + q * 256;
      int rr = e >> 4, cc = e & 15;
      int kk = k0 + cc;
      As[cc][rr] = (kk < K) ? A[(size_t)(m0 + rr) * lda + kk] : 0.f;
      Bs[cc][rr] = (kk < K) ? Wt[(size_t)(n0 + rr) * K + kk] : 0.f;
    }
    __syncthreads();
#pragma unroll
    for (int kk = 0; kk < 16; ++kk) {
      float4 av = *(const float4*)(&As[kk][ty * 4]);
      float4 bv = *(const float4*)(&Bs[kk][tx * 4]);
      float a[4] = {av.x, av.y, av.z, av.w};
      float bb[4] = {bv.x, bv.y, bv.z, bv.w};
#pragma unroll
      for (int i = 0; i < 4; ++i)
#pragma unroll
        for (int j = 0; j < 4; ++j) acc[i][j] = fmaf(a[i], bb[j], acc[i][j]);
    }
    __syncthreads();
  }

#pragma unroll
  for (int i = 0; i < 4; ++i) {
    int row = m0 + ty * 4 + i;
#pragma unroll
    for (int j = 0; j < 4; ++j) {
      int col = n0 + tx * 4 + j;
      float v = acc[i][j];
      if constexpr (FUSE) {
        float g = bn[col], be = bn[NO + col], mm = bn[2 * NO + col], va = bn[3 * NO + col];
        float s = g * rsqrtf(va + 1e-5f);
        v = fmaf(s, v - mm, be);
        v = v > 0.f ? v : 0.2f * v;
      }
      out[(size_t)row * NO + col] = v;
    }
  }
}

// ---------------------------------------------------------------- gather + k-max + BN + lrelu
__global__ void gathermax_kernel(const float* __restrict__ uv, const int* __restrict__ knn_in,
                                 const float* __restrict__ bn, int O,
                                 float* __restrict__ outc, int ldo) {
  const int n = blockIdx.x;   // global row b*N + n
  const int o = threadIdx.x;
  __shared__ int js[KNN];
  if (o < KNN) js[o] = knn_in[(size_t)n * KNN + o];
  __syncthreads();
  const int b = n >> 11;
  const int ld2 = 2 * O;
  const float* uvb = uv + (size_t)b * NPTS * ld2;
  float m = -INFINITY;
#pragma unroll
  for (int k = 0; k < KNN; ++k) m = fmaxf(m, uvb[(size_t)js[k] * ld2 + o]);
  float u = uv[(size_t)n * ld2 + O + o];
  float g = bn[o], be = bn[O + o], mm = bn[2 * O + o], va = bn[3 * O + o];
  float s = g * rsqrtf(va + 1e-5f);
  float y = fmaf(s, m + u - mm, be);
  y = y > 0.f ? y : 0.2f * y;
  outc[(size_t)n * ldo + o] = y;
}

// ---------------------------------------------------------------- final global max+avg reduce
__global__ __launch_bounds__(256) void reduce1_kernel(const float* __restrict__ feat,
                                                      float* __restrict__ part) {
  const int sp = blockIdx.x;                 // 16 splits of 128 rows
  const int b = blockIdx.z;
  const int o = blockIdx.y * 256 + threadIdx.x;
  const float* f = feat + ((size_t)b * NPTS + sp * 128) * 1024 + o;
  float mx = -INFINITY, sm = 0.f;
  for (int n = 0; n < 128; ++n) { float v = f[(size_t)n * 1024]; mx = fmaxf(mx, v); sm += v; }
  part[((size_t)(b * 16 + sp)) * 1024 + o] = mx;
  part[131072 + ((size_t)(b * 16 + sp)) * 1024 + o] = sm;
}

__global__ __launch_bounds__(256) void reduce2_kernel(const float* __restrict__ part,
                                                      float* __restrict__ out) {
  const int b = blockIdx.y;
  const int o = blockIdx.x * 256 + threadIdx.x;
  float mx = -INFINITY, sm = 0.f;
  for (int sp = 0; sp < 16; ++sp) {
    mx = fmaxf(mx, part[((size_t)(b * 16 + sp)) * 1024 + o]);
    sm += part[131072 + ((size_t)(b * 16 + sp)) * 1024 + o];
  }
  out[(size_t)b * 2048 + o] = mx;
  out[(size_t)b * 2048 + 1024 + o] = sm * (1.f / 2048.f);
}

// ---------------------------------------------------------------- launch
extern "C" void kernel_launch(void* const* d_in, const int* in_sizes, int n_in,
                              void* d_out, int out_size, void* d_ws, size_t ws_size,
                              hipStream_t stream) {
  const float* x   = (const float*)d_in[0];
  const float* W1  = (const float*)d_in[1];
  const float* W2  = (const float*)d_in[2];
  const float* W3  = (const float*)d_in[3];
  const float* W4  = (const float*)d_in[4];
  const float* W5  = (const float*)d_in[5];
  const float* bn1 = (const float*)d_in[6];
  const float* bn2 = (const float*)d_in[7];
  const float* bn3 = (const float*)d_in[8];
  const float* bn4 = (const float*)d_in[9];
  const float* bn5 = (const float*)d_in[10];
  float* out = (float*)d_out;

  char* ws = (char*)d_ws;
  float* xcat  = (float*)(ws);                 // 16384*512 f32 = 32 MiB
  float* uv    = (float*)(ws + 33554432);      // 16384*1024 f32 = 64 MiB (uv / feat)
  int*   knnb  = (int*)  (ws + 100663296);     // 16384*20 int  = 1.25 MiB
  float* sqb   = (float*)(ws + 101974016);     // 16384 f32
  float* wcat  = (float*)(ws + 102039552);     // <= 512*256 f32
  float* part  = (float*)(ws + 102563840);     // 2*8*16*1024 f32 = 1 MiB
  // kNN partial lists alias the (idle during kNN) uv region: 2 x 21 MiB < 64 MiB
  float* pd    = uv;
  int*   pi    = (int*)(ws + 33554432 + 22020096);

  const dim3 kg(NPTS / 64, 4, NBAT);   // 1024 blocks

  // ---- Layer 1: x(B,N,3) -> x1(64) @ xcat col 0
  sqnorm_kernel<<<64, 256, 0, stream>>>(x, 3, 3, sqb);
  knn2_kernel<3, 4><<<kg, 256, 0, stream>>>(x, 3, sqb, pd, pi);
  knnmerge_kernel<16><<<64, 256, 0, stream>>>(pd, pi, knnb);
  wcat_kernel<<<1, 256, 0, stream>>>(W1, 64, 3, wcat);
  gemm_kernel<false><<<dim3(256, 2), 256, 0, stream>>>(x, 3, 3, wcat, 128, uv, nullptr);
  gathermax_kernel<<<16384, 64, 0, stream>>>(uv, knnb, bn1, 64, xcat + 0, 512);

  // ---- Layer 2: x1(64) -> x2(64) @ xcat col 64
  sqnorm_kernel<<<64, 256, 0, stream>>>(xcat, 512, 64, sqb);
  knn2_kernel<64, 4><<<kg, 256, 0, stream>>>(xcat, 512, sqb, pd, pi);
  knnmerge_kernel<16><<<64, 256, 0, stream>>>(pd, pi, knnb);
  wcat_kernel<<<16, 256, 0, stream>>>(W2, 64, 64, wcat);
  gemm_kernel<false><<<dim3(256, 2), 256, 0, stream>>>(xcat, 512, 64, wcat, 128, uv, nullptr);
  gathermax_kernel<<<16384, 64, 0, stream>>>(uv, knnb, bn2, 64, xcat + 64, 512);

  // ---- Layer 3: x2(64) -> x3(128) @ xcat col 128
  sqnorm_kernel<<<64, 256, 0, stream>>>(xcat + 64, 512, 64, sqb);
  knn2_kernel<64, 4><<<kg, 256, 0, stream>>>(xcat + 64, 512, sqb, pd, pi);
  knnmerge_kernel<16><<<64, 256, 0, stream>>>(pd, pi, knnb);
  wcat_kernel<<<32, 256, 0, stream>>>(W3, 128, 64, wcat);
  gemm_kernel<false><<<dim3(256, 4), 256, 0, stream>>>(xcat + 64, 512, 64, wcat, 256, uv, nullptr);
  gathermax_kernel<<<16384, 128, 0, stream>>>(uv, knnb, bn3, 128, xcat + 128, 512);

  // ---- Layer 4: x3(128) -> x4(256) @ xcat col 256
  sqnorm_kernel<<<64, 256, 0, stream>>>(xcat + 128, 512, 128, sqb);
  knn2_kernel<128, 4><<<kg, 256, 0, stream>>>(xcat + 128, 512, sqb, pd, pi);
  knnmerge_kernel<16><<<64, 256, 0, stream>>>(pd, pi, knnb);
  wcat_kernel<<<128, 256, 0, stream>>>(W4, 256, 128, wcat);
  gemm_kernel<false><<<dim3(256, 8), 256, 0, stream>>>(xcat + 128, 512, 128, wcat, 512, uv, nullptr);
  gathermax_kernel<<<16384, 256, 0, stream>>>(uv, knnb, bn4, 256, xcat + 256, 512);

  // ---- Final MLP: feat = lrelu(bn5(xcat @ W5^T))
  gemm_kernel<true><<<dim3(256, 16), 256, 0, stream>>>(xcat, 512, 512, W5, 1024, uv, bn5);

  // ---- global max + mean over N
  reduce1_kernel<<<dim3(16, 4, 8), 256, 0, stream>>>(uv, part);
  reduce2_kernel<<<dim3(4, 8), 256, 0, stream>>>(part, out);

  (void)in_sizes; (void)n_in; (void)out_size; (void)ws_size;
}

// Round 4
// 1386.671 us; speedup vs baseline: 3.1980x; 1.4980x over previous
//
#include <hip/hip_runtime.h>
#include <hip/hip_bf16.h>
#include <math.h>

#define KNN 20
constexpr int NPTS = 2048;   // N
constexpr int NBAT = 8;      // B
constexpr int M_TOT = NBAT * NPTS;  // 16384

// ---------------------------------------------------------------- sq norms
__global__ __launch_bounds__(256) void sqnorm_kernel(const float* __restrict__ X, int lda, int C,
                                                     float* __restrict__ sq) {
  int i = blockIdx.x * 256 + threadIdx.x;
  if (i >= M_TOT) return;
  const float* p = X + (size_t)i * lda;
  float s = 0.f;
  for (int c = 0; c < C; ++c) { float v = p[c]; s = fmaf(v, v, s); }
  sq[i] = s;
}

// ---------------------------------------------------------------- top-20 sorted insert (swap chain)
#define INSERT_CAND(key_, j_)                                  \
  if ((key_) < dl[KNN - 1]) {                                  \
    float _k = (key_); int _j = (j_);                          \
    _Pragma("unroll")                                          \
    for (int p = 0; p < KNN; ++p) {                            \
      bool sw = _k < dl[p];                                    \
      float od = dl[p]; int oi = il[p];                        \
      dl[p] = sw ? _k : od; il[p] = sw ? _j : oi;              \
      _k = sw ? od : _k; _j = sw ? oi : _j;                    \
    }                                                          \
  }

// ---------------------------------------------------------------- kNN v3 (fixed C==3 staging)
// Block: 256 thr. Tile: 32 rows x 64 cands/chunk (micro 2x4), CSPLIT=4 cand splits.
// Select: 8 lanes/row (stream = 64 steps). In-kernel LDS 8-way merge ->
// one sorted top-20 per (row, split).
template <int C, int CSPLIT>
__global__ __launch_bounds__(256) void knn3_kernel(const float* __restrict__ X, int lda,
                                                   const float* __restrict__ sq,
                                                   float* __restrict__ pd, int* __restrict__ pi) {
  constexpr int ROWS = 32, CHK = 64, KB = 32, SEL = 8;
  constexpr int KP = KB + 4;                  // staging stride (f4-aligned, padded)
  constexpr int DP = CHK + 1;                 // 65: dist stride -> 2-way (free) on select
  constexpr int NKB = (C == 3) ? 1 : C / KB;
  constexpr int XI_W = (C == 3) ? 4 : KP;
  __shared__ __align__(16) float smem[10240];          // 40 KiB -> 4 blocks/CU
  float* xi = smem;                                    // [ROWS][XI_W]
  float* xj = smem + ROWS * XI_W;                      // [CHK][XI_W]
  float* dist = smem + (ROWS + CHK) * XI_W;            // [ROWS][DP]
  float* mbufd = smem;                                 // aliased after barrier
  int* mbufi = (int*)(smem + ROWS * SEL * KNN);        // [ROWS][SEL][KNN]

  const int b = blockIdx.z;
  const int m0 = blockIdx.x * ROWS;
  const int jsplit = blockIdx.y * (NPTS / CSPLIT);
  const int t = threadIdx.x;
  const int tx = t & 15, ty = t >> 4;         // compute roles: rows ty+16i, cols tx+16j
  const int sr = t >> 3, ss = t & 7;          // select roles: row sr, col-slice ss
  const float* Xb = X + (size_t)b * NPTS * lda;
  const float* sqb = sq + b * NPTS;

  float dl[KNN]; int il[KNN];
#pragma unroll
  for (int p = 0; p < KNN; ++p) { dl[p] = INFINITY; il[p] = 0x7fffffff; }

  for (int c0 = 0; c0 < NPTS / CSPLIT; c0 += CHK) {
    const int jb = jsplit + c0;
    float acc[2][4] = {};

    if constexpr (C == 3) {
      __syncthreads();
      // full-coverage grid-stride staging (96 + 192 elements, 256 threads)
      for (int e = t; e < ROWS * 3; e += 256) {
        int rr = e / 3, cc = e % 3;
        xi[rr * 4 + cc] = Xb[(size_t)(m0 + rr) * lda + cc];
      }
      for (int e = t; e < CHK * 3; e += 256) {
        int rr = e / 3, cc = e % 3;
        xj[rr * 4 + cc] = Xb[(size_t)(jb + rr) * lda + cc];
      }
      __syncthreads();
#pragma unroll
      for (int i = 0; i < 2; ++i) {
        const float* xr = xi + (ty + 16 * i) * 4;
        float x0 = xr[0], x1 = xr[1], x2 = xr[2];
#pragma unroll
        for (int j = 0; j < 4; ++j) {
          const float* xc = xj + (tx + 16 * j) * 4;
          acc[i][j] = fmaf(x0, xc[0], fmaf(x1, xc[1], x2 * xc[2]));
        }
      }
    } else {
#pragma unroll
      for (int kb = 0; kb < NKB; ++kb) {
        __syncthreads();
        // stage xi 32x32 (256 f4) + xj 64x32 (512 f4): 3 f4 per thread
#pragma unroll
        for (int q = 0; q < 3; ++q) {
          if (q == 0) {
            int rr = t >> 3, cc = t & 7;
            *(float4*)(xi + rr * KP + cc * 4) =
                *(const float4*)(Xb + (size_t)(m0 + rr) * lda + kb * KB + cc * 4);
          } else {
            int f = t + (q - 1) * 256;
            int rr = f >> 3, cc = f & 7;
            *(float4*)(xj + rr * KP + cc * 4) =
                *(const float4*)(Xb + (size_t)(jb + rr) * lda + kb * KB + cc * 4);
          }
        }
        __syncthreads();
#pragma unroll
        for (int k4 = 0; k4 < KB / 4; ++k4) {
          float4 av[2], bv[4];
#pragma unroll
          for (int i = 0; i < 2; ++i) av[i] = *(const float4*)(xi + (ty + 16 * i) * KP + k4 * 4);
#pragma unroll
          for (int j = 0; j < 4; ++j) bv[j] = *(const float4*)(xj + (tx + 16 * j) * KP + k4 * 4);
#pragma unroll
          for (int i = 0; i < 2; ++i)
#pragma unroll
            for (int j = 0; j < 4; ++j) {
              acc[i][j] = fmaf(av[i].x, bv[j].x, acc[i][j]);
              acc[i][j] = fmaf(av[i].y, bv[j].y, acc[i][j]);
              acc[i][j] = fmaf(av[i].z, bv[j].z, acc[i][j]);
              acc[i][j] = fmaf(av[i].w, bv[j].w, acc[i][j]);
            }
        }
      }
    }

    // ranking key: sq_j - 2*dot (same fma order as v2 -> bit-identical keys)
    float sqv[4];
#pragma unroll
    for (int j = 0; j < 4; ++j) sqv[j] = sqb[jb + tx + 16 * j];
#pragma unroll
    for (int i = 0; i < 2; ++i)
#pragma unroll
      for (int j = 0; j < 4; ++j)
        dist[(ty + 16 * i) * DP + tx + 16 * j] = fmaf(-2.f, acc[i][j], sqv[j]);
    __syncthreads();

    // select: 8 lanes/row, each scans 8 cands (ascending j within lane)
#pragma unroll
    for (int q = 0; q < 8; ++q) {
      float key = dist[sr * DP + ss * 8 + q];
      int jidx = jb + ss * 8 + q;
      INSERT_CAND(key, jidx)
    }
  }

  // dump per-lane lists to LDS (aliases staging/dist regions)
  __syncthreads();
#pragma unroll
  for (int p = 0; p < KNN; ++p) {
    mbufd[(sr * SEL + ss) * KNN + p] = dl[p];
    mbufi[(sr * SEL + ss) * KNN + p] = il[p];
  }
  __syncthreads();

  // in-kernel exact 8-way lex merge: one thread per row
  if (t < ROWS) {
    int p[SEL];
#pragma unroll
    for (int g = 0; g < SEL; ++g) p[g] = 0;
    const size_t base = ((size_t)(b * NPTS + m0 + t) * CSPLIT + blockIdx.y) * KNN;
    for (int k = 0; k < KNN; ++k) {
      float bd = INFINITY; int bi = 0x7fffffff; int bg = 0;
#pragma unroll
      for (int g = 0; g < SEL; ++g) {
        float dd = mbufd[(t * SEL + g) * KNN + p[g]];
        int iv = mbufi[(t * SEL + g) * KNN + p[g]];
        if (dd < bd || (dd == bd && iv < bi)) { bd = dd; bi = iv; bg = g; }
      }
      pd[base + k] = bd;
      pi[base + k] = bi;
#pragma unroll
      for (int g = 0; g < SEL; ++g) p[g] += (bg == g) ? 1 : 0;
    }
  }
}

// ---------------------------------------------------------------- exact NL-way merge of sorted lists
template <int NL>
__global__ __launch_bounds__(256) void knnmerge_kernel(const float* __restrict__ pd,
                                                       const int* __restrict__ pi,
                                                       int* __restrict__ knn_out) {
  int row = blockIdx.x * 256 + threadIdx.x;
  if (row >= M_TOT) return;
  const float* d = pd + (size_t)row * NL * KNN;
  const int* ii = pi + (size_t)row * NL * KNN;
  int p[NL];
#pragma unroll
  for (int g = 0; g < NL; ++g) p[g] = 0;
  int* orow = knn_out + (size_t)row * KNN;
  for (int k = 0; k < KNN; ++k) {
    float bd = INFINITY; int bi = 0x7fffffff; int bg = 0;
#pragma unroll
    for (int g = 0; g < NL; ++g) {
      float dd = d[g * KNN + p[g]];
      int iv = ii[g * KNN + p[g]];
      if (dd < bd || (dd == bd && iv < bi)) { bd = dd; bi = iv; bg = g; }
    }
    orow[k] = bi;
#pragma unroll
    for (int g = 0; g < NL; ++g) p[g] += (bg == g) ? 1 : 0;   // static-index update
  }
}

// ---------------------------------------------------------------- weight prep: [Wd ; Wc-Wd]
__global__ __launch_bounds__(256) void wcat_kernel(const float* __restrict__ W, int O, int Cc,
                                                   float* __restrict__ out) {
  int i = blockIdx.x * 256 + threadIdx.x;
  if (i >= O * Cc) return;
  int o = i / Cc, c = i % Cc;
  float wd = W[(size_t)o * 2 * Cc + c];
  float wc = W[(size_t)o * 2 * Cc + Cc + c];
  out[(size_t)o * Cc + c] = wd;              // rows 0..O-1   : v = Wd * x
  out[(size_t)(O + o) * Cc + c] = wc - wd;   // rows O..2O-1  : u = (Wc-Wd) * x
}

// ---------------------------------------------------------------- fp32 tiled GEMM
// out[M, NO] = A[M, K](lda) @ Wt[NO, K]^T ;  BM=BN=64, BK=16, 256 thr, 4x4 micro-tile
template <bool FUSE>
__global__ __launch_bounds__(256) void gemm_kernel(const float* __restrict__ A, int lda, int K,
                                                   const float* __restrict__ Wt, int NO,
                                                   float* __restrict__ out,
                                                   const float* __restrict__ bn) {
  __shared__ float As[16][68];
  __shared__ float Bs[16][68];
  const int t = threadIdx.x;
  const int tx = t & 15, ty = t >> 4;
  const int m0 = blockIdx.x * 64, n0 = blockIdx.y * 64;
  float acc[4][4] = {};

  for (int k0 = 0; k0 < K; k0 += 16) {
#pragma unroll
    for (int q = 0; q < 4; ++q) {
      int e = t + q * 256;
      int rr = e >> 4, cc = e & 15;
      int kk = k0 + cc;
      As[cc][rr] = (kk < K) ? A[(size_t)(m0 + rr) * lda + kk] : 0.f;
      Bs[cc][rr] = (kk < K) ? Wt[(size_t)(n0 + rr) * K + kk] : 0.f;
    }
    __syncthreads();
#pragma unroll
    for (int kk = 0; kk < 16; ++kk) {
      float4 av = *(const float4*)(&As[kk][ty * 4]);
      float4 bv = *(const float4*)(&Bs[kk][tx * 4]);
      float a[4] = {av.x, av.y, av.z, av.w};
      float bb[4] = {bv.x, bv.y, bv.z, bv.w};
#pragma unroll
      for (int i = 0; i < 4; ++i)
#pragma unroll
        for (int j = 0; j < 4; ++j) acc[i][j] = fmaf(a[i], bb[j], acc[i][j]);
    }
    __syncthreads();
  }

#pragma unroll
  for (int i = 0; i < 4; ++i) {
    int row = m0 + ty * 4 + i;
#pragma unroll
    for (int j = 0; j < 4; ++j) {
      int col = n0 + tx * 4 + j;
      float v = acc[i][j];
      if constexpr (FUSE) {
        float g = bn[col], be = bn[NO + col], mm = bn[2 * NO + col], va = bn[3 * NO + col];
        float s = g * rsqrtf(va + 1e-5f);
        v = fmaf(s, v - mm, be);
        v = v > 0.f ? v : 0.2f * v;
      }
      out[(size_t)row * NO + col] = v;
    }
  }
}

// ---------------------------------------------------------------- gather + k-max + BN + lrelu
__global__ void gathermax_kernel(const float* __restrict__ uv, const int* __restrict__ knn_in,
                                 const float* __restrict__ bn, int O,
                                 float* __restrict__ outc, int ldo) {
  const int n = blockIdx.x;   // global row b*N + n
  const int o = threadIdx.x;
  __shared__ int js[KNN];
  if (o < KNN) js[o] = knn_in[(size_t)n * KNN + o];
  __syncthreads();
  const int b = n >> 11;
  const int ld2 = 2 * O;
  const float* uvb = uv + (size_t)b * NPTS * ld2;
  float m = -INFINITY;
#pragma unroll
  for (int k = 0; k < KNN; ++k) m = fmaxf(m, uvb[(size_t)js[k] * ld2 + o]);
  float u = uv[(size_t)n * ld2 + O + o];
  float g = bn[o], be = bn[O + o], mm = bn[2 * O + o], va = bn[3 * O + o];
  float s = g * rsqrtf(va + 1e-5f);
  float y = fmaf(s, m + u - mm, be);
  y = y > 0.f ? y : 0.2f * y;
  outc[(size_t)n * ldo + o] = y;
}

// ---------------------------------------------------------------- final global max+avg reduce
__global__ __launch_bounds__(256) void reduce1_kernel(const float* __restrict__ feat,
                                                      float* __restrict__ part) {
  const int sp = blockIdx.x;                 // 16 splits of 128 rows
  const int b = blockIdx.z;
  const int o = blockIdx.y * 256 + threadIdx.x;
  const float* f = feat + ((size_t)b * NPTS + sp * 128) * 1024 + o;
  float mx = -INFINITY, sm = 0.f;
  for (int n = 0; n < 128; ++n) { float v = f[(size_t)n * 1024]; mx = fmaxf(mx, v); sm += v; }
  part[((size_t)(b * 16 + sp)) * 1024 + o] = mx;
  part[131072 + ((size_t)(b * 16 + sp)) * 1024 + o] = sm;
}

__global__ __launch_bounds__(256) void reduce2_kernel(const float* __restrict__ part,
                                                      float* __restrict__ out) {
  const int b = blockIdx.y;
  const int o = blockIdx.x * 256 + threadIdx.x;
  float mx = -INFINITY, sm = 0.f;
  for (int sp = 0; sp < 16; ++sp) {
    mx = fmaxf(mx, part[((size_t)(b * 16 + sp)) * 1024 + o]);
    sm += part[131072 + ((size_t)(b * 16 + sp)) * 1024 + o];
  }
  out[(size_t)b * 2048 + o] = mx;
  out[(size_t)b * 2048 + 1024 + o] = sm * (1.f / 2048.f);
}

// ---------------------------------------------------------------- launch
extern "C" void kernel_launch(void* const* d_in, const int* in_sizes, int n_in,
                              void* d_out, int out_size, void* d_ws, size_t ws_size,
                              hipStream_t stream) {
  const float* x   = (const float*)d_in[0];
  const float* W1  = (const float*)d_in[1];
  const float* W2  = (const float*)d_in[2];
  const float* W3  = (const float*)d_in[3];
  const float* W4  = (const float*)d_in[4];
  const float* W5  = (const float*)d_in[5];
  const float* bn1 = (const float*)d_in[6];
  const float* bn2 = (const float*)d_in[7];
  const float* bn3 = (const float*)d_in[8];
  const float* bn4 = (const float*)d_in[9];
  const float* bn5 = (const float*)d_in[10];
  float* out = (float*)d_out;

  char* ws = (char*)d_ws;
  float* xcat  = (float*)(ws);                 // 16384*512 f32 = 32 MiB
  float* uv    = (float*)(ws + 33554432);      // 16384*1024 f32 = 64 MiB (uv / feat)
  int*   knnb  = (int*)  (ws + 100663296);     // 16384*20 int  = 1.25 MiB
  float* sqb   = (float*)(ws + 101974016);     // 16384 f32
  float* wcat  = (float*)(ws + 102039552);     // <= 512*256 f32
  float* part  = (float*)(ws + 102563840);     // 2*8*16*1024 f32 = 1 MiB
  // kNN partial lists alias the (idle during kNN) uv region: 2 x 5.25 MiB
  float* pd    = uv;
  int*   pi    = (int*)(ws + 33554432 + 22020096);

  const dim3 kg(NPTS / 32, 4, NBAT);   // 2048 blocks

  // ---- Layer 1: x(B,N,3) -> x1(64) @ xcat col 0
  sqnorm_kernel<<<64, 256, 0, stream>>>(x, 3, 3, sqb);
  knn3_kernel<3, 4><<<kg, 256, 0, stream>>>(x, 3, sqb, pd, pi);
  knnmerge_kernel<4><<<64, 256, 0, stream>>>(pd, pi, knnb);
  wcat_kernel<<<1, 256, 0, stream>>>(W1, 64, 3, wcat);
  gemm_kernel<false><<<dim3(256, 2), 256, 0, stream>>>(x, 3, 3, wcat, 128, uv, nullptr);
  gathermax_kernel<<<16384, 64, 0, stream>>>(uv, knnb, bn1, 64, xcat + 0, 512);

  // ---- Layer 2: x1(64) -> x2(64) @ xcat col 64
  sqnorm_kernel<<<64, 256, 0, stream>>>(xcat, 512, 64, sqb);
  knn3_kernel<64, 4><<<kg, 256, 0, stream>>>(xcat, 512, sqb, pd, pi);
  knnmerge_kernel<4><<<64, 256, 0, stream>>>(pd, pi, knnb);
  wcat_kernel<<<16, 256, 0, stream>>>(W2, 64, 64, wcat);
  gemm_kernel<false><<<dim3(256, 2), 256, 0, stream>>>(xcat, 512, 64, wcat, 128, uv, nullptr);
  gathermax_kernel<<<16384, 64, 0, stream>>>(uv, knnb, bn2, 64, xcat + 64, 512);

  // ---- Layer 3: x2(64) -> x3(128) @ xcat col 128
  sqnorm_kernel<<<64, 256, 0, stream>>>(xcat + 64, 512, 64, sqb);
  knn3_kernel<64, 4><<<kg, 256, 0, stream>>>(xcat + 64, 512, sqb, pd, pi);
  knnmerge_kernel<4><<<64, 256, 0, stream>>>(pd, pi, knnb);
  wcat_kernel<<<32, 256, 0, stream>>>(W3, 128, 64, wcat);
  gemm_kernel<false><<<dim3(256, 4), 256, 0, stream>>>(xcat + 64, 512, 64, wcat, 256, uv, nullptr);
  gathermax_kernel<<<16384, 128, 0, stream>>>(uv, knnb, bn3, 128, xcat + 128, 512);

  // ---- Layer 4: x3(128) -> x4(256) @ xcat col 256
  sqnorm_kernel<<<64, 256, 0, stream>>>(xcat + 128, 512, 128, sqb);
  knn3_kernel<128, 4><<<kg, 256, 0, stream>>>(xcat + 128, 512, sqb, pd, pi);
  knnmerge_kernel<4><<<64, 256, 0, stream>>>(pd, pi, knnb);
  wcat_kernel<<<128, 256, 0, stream>>>(W4, 256, 128, wcat);
  gemm_kernel<false><<<dim3(256, 8), 256, 0, stream>>>(xcat + 128, 512, 128, wcat, 512, uv, nullptr);
  gathermax_kernel<<<16384, 256, 0, stream>>>(uv, knnb, bn4, 256, xcat + 256, 512);

  // ---- Final MLP: feat = lrelu(bn5(xcat @ W5^T))
  gemm_kernel<true><<<dim3(256, 16), 256, 0, stream>>>(xcat, 512, 512, W5, 1024, uv, bn5);

  // ---- global max + mean over N
  reduce1_kernel<<<dim3(16, 4, 8), 256, 0, stream>>>(uv, part);
  reduce2_kernel<<<dim3(4, 8), 256, 0, stream>>>(part, out);

  (void)in_sizes; (void)n_in; (void)out_size; (void)ws_size;
}